// Round 1
// baseline (4493.248 us; speedup 1.0000x reference)
//
#include <hip/hip_runtime.h>
#include <stdint.h>
#include <stddef.h>

// ESTHead: B=4 S=2048 HID=4096 H=32 D=128
// Pipeline:
//   f2b(X, Wk, Wv) -> bf16
//   gemm_rope: k = rope(X@Wk^T), v = rope(X@Wv^T)   [bf16 MFMA 16x16x32, 128x128 tile, BK=64]
//   scores = eq . k ; softmax ; attn_out = p . v
//   fp32 skinny tail: Wo -> LN -> (W0,W1,SiLU) -> W2 -> LN -> Ws + bs

#define BB 4
#define SS 2048
#define HIDDIM 4096
#define NH 32
#define HD 128
#define MROWS (BB * SS)  // 8192

typedef __attribute__((ext_vector_type(8))) __bf16 bf16x8;
typedef __attribute__((ext_vector_type(4))) float f32x4;

static __device__ __forceinline__ unsigned short f2bf(float f) {
  union { float f; unsigned u; } c; c.f = f;
  unsigned u = c.u;
  u += 0x7fffu + ((u >> 16) & 1u);
  return (unsigned short)(u >> 16);
}
static __device__ __forceinline__ float bf2f(unsigned short h) {
  union { unsigned u; float f; } c; c.u = ((unsigned)h) << 16;
  return c.f;
}

__global__ __launch_bounds__(256) void f2b_kernel(const float4* __restrict__ in,
                                                  ushort4* __restrict__ out, int n4) {
  int stride = gridDim.x * blockDim.x;
  for (int i = blockIdx.x * blockDim.x + threadIdx.x; i < n4; i += stride) {
    float4 v = in[i];
    ushort4 o;
    o.x = f2bf(v.x); o.y = f2bf(v.y); o.z = f2bf(v.z); o.w = f2bf(v.w);
    out[i] = o;
  }
}

static __device__ __forceinline__ void load16_lds(const void* g, void* l) {
  __builtin_amdgcn_global_load_lds(
      (const __attribute__((address_space(1))) unsigned int*)g,
      (__attribute__((address_space(3))) unsigned int*)l, 16, 0, 0);
}

// C = rope(A @ W^T) in bf16. A: 8192x4096 bf16, W: 4096x4096 bf16 (both K-contiguous).
// Block: 256 thr = 4 waves (2x2), 128x128 tile, BK=64, single LDS buffer, 2 barriers/iter.
// LDS chunk XOR-swizzle: [row][chunk j] slot holds global chunk (j ^ (row&7)) so the
// ds_read_b128 fragment reads hit <=2-way bank conflicts (free) despite no padding.
__global__ __launch_bounds__(256) void gemm_rope_kernel(
    const unsigned short* __restrict__ A,
    const unsigned short* __restrict__ W,
    unsigned short* __restrict__ C) {
  __shared__ __align__(16) unsigned char smem[32768];
  unsigned char* sA = smem;
  unsigned char* sB = smem + 16384;

  const int tid  = threadIdx.x;
  const int wave = tid >> 6;
  const int lane = tid & 63;
  const int wm = wave >> 1, wn = wave & 1;
  const int quad = lane >> 4, l15 = lane & 15;
  const int bm = blockIdx.y, bn = blockIdx.x;

  f32x4 acc[4][4];
#pragma unroll
  for (int i = 0; i < 4; ++i)
#pragma unroll
    for (int j = 0; j < 4; ++j)
      acc[i][j] = (f32x4){0.f, 0.f, 0.f, 0.f};

  const int crow = lane >> 3;      // row within 8-row staging chunk
  const int jj   = lane & 7;       // LDS 16B slot within row
  const int scol = jj ^ crow;      // swizzled global chunk to fetch
  const unsigned short* Abase = A + (size_t)(bm * 128) * HIDDIM;
  const unsigned short* Wbase = W + (size_t)(bn * 128) * HIDDIM;

  for (int kt = 0; kt < HIDDIM; kt += 64) {
#pragma unroll
    for (int it = 0; it < 4; ++it) {
      int rt = wave * 32 + it * 8 + crow;          // tile row 0..127
      int lo = (wave * 4 + it) * 1024;             // wave-uniform LDS chunk base
      load16_lds(Abase + (size_t)rt * HIDDIM + kt + scol * 8, sA + lo);
      load16_lds(Wbase + (size_t)rt * HIDDIM + kt + scol * 8, sB + lo);
    }
    __syncthreads();  // vmcnt(0) drain + barrier: LDS tiles ready
#pragma unroll
    for (int ks = 0; ks < 2; ++ks) {
      const int ch = ((ks * 4 + quad) ^ (l15 & 7)) * 16;
      bf16x8 af[4], bfr[4];
#pragma unroll
      for (int i = 0; i < 4; ++i) {
        int arow = wm * 64 + i * 16 + l15;
        af[i] = *(const bf16x8*)(sA + arow * 128 + ch);
      }
#pragma unroll
      for (int j = 0; j < 4; ++j) {
        int brow = wn * 64 + j * 16 + l15;
        bfr[j] = *(const bf16x8*)(sB + brow * 128 + ch);
      }
#pragma unroll
      for (int i = 0; i < 4; ++i)
#pragma unroll
        for (int j = 0; j < 4; ++j)
          acc[i][j] = __builtin_amdgcn_mfma_f32_16x16x32_bf16(af[i], bfr[j], acc[i][j], 0, 0, 0);
    }
    __syncthreads();  // all waves done reading before next overwrite
  }

  // Epilogue: RoPE + bf16 store. C/D layout: col = lane&15, row = quad*4 + reg.
  // N-tile (128) == head dim, so d = col_local; RoPE pair (2i,2i+1) = adjacent lanes.
  const int colb = bn * 128;
#pragma unroll
  for (int j = 0; j < 4; ++j) {
    const int col_local = wn * 64 + j * 16 + l15;  // == d in [0,128)
    const int ip  = col_local >> 1;
    const int odd = col_local & 1;
    // theta = 10000^(-ip/64) = 2^(-ip * log2(10000)/64)
    const float theta = exp2f(-0.2076205059304601f * (float)ip);
#pragma unroll
    for (int i = 0; i < 4; ++i) {
#pragma unroll
      for (int r = 0; r < 4; ++r) {
        int token = bm * 128 + wm * 64 + i * 16 + quad * 4 + r;
        int spos  = token & (SS - 1);
        float val = acc[i][j][r];
        float oth = __shfl_xor(val, 1);
        float sn, cs;
        sincosf((float)spos * theta, &sn, &cs);
        float o = odd ? (val * cs + oth * sn) : (val * cs - oth * sn);
        C[(size_t)token * HIDDIM + colb + col_local] = f2bf(o);
      }
    }
  }
}

// scores[b,h,s] = sum_d eq[h,d] * k[b,s,h,d]; one wave per (b,h,s)
__global__ __launch_bounds__(256) void scores_kernel(const unsigned short* __restrict__ kb,
                                                     const float* __restrict__ eq,
                                                     float* __restrict__ scores) {
  int gw   = blockIdx.x * 4 + (threadIdx.x >> 6);  // (b*32+h)*2048 + s
  int lane = threadIdx.x & 63;
  int s = gw & (SS - 1);
  int h = (gw >> 11) & (NH - 1);
  int b = gw >> 16;
  const unsigned short* kp = kb + (size_t)(b * SS + s) * HIDDIM + h * HD + lane * 2;
  const float* qp = eq + h * HD + lane * 2;
  float p = bf2f(kp[0]) * qp[0] + bf2f(kp[1]) * qp[1];
#pragma unroll
  for (int off = 32; off > 0; off >>= 1) p += __shfl_down(p, off);
  if (lane == 0) scores[gw] = p;
}

// One block per (b,h): softmax over S then attn_out[d] = sum_s p_s * v[b,s,h,d]
__global__ __launch_bounds__(256) void softmax_av_kernel(const float* __restrict__ scores,
                                                         const unsigned short* __restrict__ vb,
                                                         float* __restrict__ attn_out) {
  __shared__ float p[SS];
  __shared__ float red[8];
  __shared__ float acc2[HD];
  const int bh = blockIdx.x, b = bh >> 5, h = bh & 31;
  const int tid = threadIdx.x, lane = tid & 63, wave = tid >> 6;
  const float* sc = scores + (size_t)bh * SS;

  float m = -1e30f;
  for (int i = tid; i < SS; i += 256) m = fmaxf(m, sc[i]);
#pragma unroll
  for (int off = 32; off > 0; off >>= 1) m = fmaxf(m, __shfl_down(m, off));
  if (lane == 0) red[wave] = m;
  __syncthreads();
  if (tid == 0) red[4] = fmaxf(fmaxf(red[0], red[1]), fmaxf(red[2], red[3]));
  __syncthreads();
  const float M = red[4];

  float lsum = 0.f;
  for (int i = tid; i < SS; i += 256) { float e = expf(sc[i] - M); p[i] = e; lsum += e; }
#pragma unroll
  for (int off = 32; off > 0; off >>= 1) lsum += __shfl_down(lsum, off);
  __syncthreads();
  if (lane == 0) red[wave] = lsum;
  __syncthreads();
  const float Ssum = red[0] + red[1] + red[2] + red[3];

  const int d = tid & 127, half = tid >> 7;
  const unsigned short* vp = vb + (size_t)(b * SS) * HIDDIM + h * HD + d;
  float a = 0.f;
  const int s0 = half * 1024;
#pragma unroll 4
  for (int s = s0; s < s0 + 1024; ++s) a += p[s] * bf2f(vp[(size_t)s * HIDDIM]);
  if (half) acc2[d] = a;
  __syncthreads();
  if (!half) attn_out[(size_t)b * HIDDIM + h * HD + d] = (a + acc2[d]) / Ssum;
}

// y[b,n] = sum_k x[b,k]*W[n,k] (+bias). x: 4xK fp32. One wave per n.
__global__ __launch_bounds__(256) void skinny_kernel(const float* __restrict__ W,
                                                     const float* __restrict__ x,
                                                     float* __restrict__ y,
                                                     int N, int K,
                                                     const float* __restrict__ bias) {
  int n = blockIdx.x * 4 + (threadIdx.x >> 6);
  int lane = threadIdx.x & 63;
  const float* w  = W + (size_t)n * K;
  const float* x1 = x + K, * x2 = x + 2 * K, * x3 = x + 3 * K;
  float a0 = 0.f, a1 = 0.f, a2 = 0.f, a3 = 0.f;
#pragma unroll 4
  for (int k = lane; k < K; k += 64) {
    float wv = w[k];
    a0 += wv * x[k]; a1 += wv * x1[k]; a2 += wv * x2[k]; a3 += wv * x3[k];
  }
#pragma unroll
  for (int off = 32; off > 0; off >>= 1) {
    a0 += __shfl_down(a0, off); a1 += __shfl_down(a1, off);
    a2 += __shfl_down(a2, off); a3 += __shfl_down(a3, off);
  }
  if (lane == 0) {
    float bv = bias ? bias[n] : 0.f;
    y[n] = a0 + bv; y[N + n] = a1 + bv; y[2 * N + n] = a2 + bv; y[3 * N + n] = a3 + bv;
  }
}

// c[b,n] = (x@W0^T) * silu(x@W1^T), fused
__global__ __launch_bounds__(256) void skinny_glu_kernel(const float* __restrict__ W0,
                                                         const float* __restrict__ W1,
                                                         const float* __restrict__ x,
                                                         float* __restrict__ c,
                                                         int N, int K) {
  int n = blockIdx.x * 4 + (threadIdx.x >> 6);
  int lane = threadIdx.x & 63;
  const float* w0 = W0 + (size_t)n * K;
  const float* w1 = W1 + (size_t)n * K;
  const float* x1 = x + K, * x2 = x + 2 * K, * x3 = x + 3 * K;
  float a0 = 0.f, a1 = 0.f, a2 = 0.f, a3 = 0.f;
  float g0 = 0.f, g1 = 0.f, g2 = 0.f, g3 = 0.f;
#pragma unroll 2
  for (int k = lane; k < K; k += 64) {
    float wa = w0[k], wg = w1[k];
    float v0 = x[k], v1 = x1[k], v2 = x2[k], v3 = x3[k];
    a0 += wa * v0; a1 += wa * v1; a2 += wa * v2; a3 += wa * v3;
    g0 += wg * v0; g1 += wg * v1; g2 += wg * v2; g3 += wg * v3;
  }
#pragma unroll
  for (int off = 32; off > 0; off >>= 1) {
    a0 += __shfl_down(a0, off); a1 += __shfl_down(a1, off);
    a2 += __shfl_down(a2, off); a3 += __shfl_down(a3, off);
    g0 += __shfl_down(g0, off); g1 += __shfl_down(g1, off);
    g2 += __shfl_down(g2, off); g3 += __shfl_down(g3, off);
  }
  if (lane == 0) {
    c[n]         = a0 * (g0 / (1.f + expf(-g0)));
    c[N + n]     = a1 * (g1 / (1.f + expf(-g1)));
    c[2 * N + n] = a2 * (g2 / (1.f + expf(-g2)));
    c[3 * N + n] = a3 * (g3 / (1.f + expf(-g3)));
  }
}

__global__ __launch_bounds__(256) void ln_kernel(const float* __restrict__ x,
                                                 const float* __restrict__ g,
                                                 const float* __restrict__ bta,
                                                 float* __restrict__ y) {
  __shared__ float rs[8], rs2[8];
  const int b = blockIdx.x, tid = threadIdx.x, lane = tid & 63, wave = tid >> 6;
  const float* xr = x + (size_t)b * HIDDIM;
  float s = 0.f, s2 = 0.f;
  for (int i = tid; i < HIDDIM; i += 256) { float v = xr[i]; s += v; s2 += v * v; }
#pragma unroll
  for (int off = 32; off > 0; off >>= 1) { s += __shfl_down(s, off); s2 += __shfl_down(s2, off); }
  if (lane == 0) { rs[wave] = s; rs2[wave] = s2; }
  __syncthreads();
  if (tid == 0) { rs[4] = rs[0] + rs[1] + rs[2] + rs[3]; rs2[4] = rs2[0] + rs2[1] + rs2[2] + rs2[3]; }
  __syncthreads();
  const float mu = rs[4] * (1.f / HIDDIM);
  const float var = rs2[4] * (1.f / HIDDIM) - mu * mu;
  const float rstd = rsqrtf(var + 1e-5f);
  float* yr = y + (size_t)b * HIDDIM;
  for (int i = tid; i < HIDDIM; i += 256) yr[i] = (xr[i] - mu) * rstd * g[i] + bta[i];
}

extern "C" void kernel_launch(void* const* d_in, const int* in_sizes, int n_in,
                              void* d_out, int out_size, void* d_ws, size_t ws_size,
                              hipStream_t stream) {
  const float* hidden = (const float*)d_in[0];
  const float* eq     = (const float*)d_in[1];
  const float* Wk     = (const float*)d_in[2];
  const float* Wv     = (const float*)d_in[3];
  const float* Wo     = (const float*)d_in[4];
  const float* W0     = (const float*)d_in[5];
  const float* W1     = (const float*)d_in[6];
  const float* W2     = (const float*)d_in[7];
  const float* Ws     = (const float*)d_in[8];
  const float* bs     = (const float*)d_in[9];
  const float* ln_g   = (const float*)d_in[10];
  const float* ln_b   = (const float*)d_in[11];
  float* out = (float*)d_out;

  char* ws = (char*)d_ws;
  unsigned short* Xb   = (unsigned short*)(ws);               // 8192x4096 bf16 = 64 MiB
  unsigned short* Wkb  = (unsigned short*)(ws + 67108864);    // 32 MiB
  unsigned short* Wvb  = (unsigned short*)(ws + 100663296);   // 32 MiB
  unsigned short* kb   = (unsigned short*)(ws + 134217728);   // 64 MiB (roped k, bf16)
  unsigned short* vb   = (unsigned short*)(ws + 201326592);   // 64 MiB (roped v, bf16)
  float* scores  = (float*)(ws + 268435456);                  // 4*32*2048 fp32 = 1 MiB
  float* attn    = (float*)(ws + 269484032);                  // 4x4096
  float* y1      = (float*)(ws + 269549568);
  float* x1      = (float*)(ws + 269615104);
  float* cbuf    = (float*)(ws + 269680640);                  // 4x12288
  float* y2      = (float*)(ws + 269877248);
  float* x2      = (float*)(ws + 269942784);
  (void)in_sizes; (void)n_in; (void)out_size; (void)ws_size;

  f2b_kernel<<<8192, 256, 0, stream>>>((const float4*)hidden, (ushort4*)Xb, (MROWS * HIDDIM) / 4);
  f2b_kernel<<<4096, 256, 0, stream>>>((const float4*)Wk, (ushort4*)Wkb, (4096 * HIDDIM) / 4);
  f2b_kernel<<<4096, 256, 0, stream>>>((const float4*)Wv, (ushort4*)Wvb, (4096 * HIDDIM) / 4);

  dim3 gg(32, 64);  // bn x bm
  gemm_rope_kernel<<<gg, 256, 0, stream>>>(Xb, Wkb, kb);
  gemm_rope_kernel<<<gg, 256, 0, stream>>>(Xb, Wvb, vb);

  scores_kernel<<<(BB * NH * SS) / 4, 256, 0, stream>>>(kb, eq, scores);
  softmax_av_kernel<<<BB * NH, 256, 0, stream>>>(scores, vb, attn);

  skinny_kernel<<<4096 / 4, 256, 0, stream>>>(Wo, attn, y1, 4096, 4096, nullptr);
  ln_kernel<<<BB, 256, 0, stream>>>(y1, ln_g, ln_b, x1);
  skinny_glu_kernel<<<12288 / 4, 256, 0, stream>>>(W0, W1, x1, cbuf, 12288, 4096);
  skinny_kernel<<<4096 / 4, 256, 0, stream>>>(W2, cbuf, y2, 4096, 12288, nullptr);
  ln_kernel<<<BB, 256, 0, stream>>>(y2, ln_g, ln_b, x2);
  skinny_kernel<<<2048 / 4, 256, 0, stream>>>(Ws, x2, out, 2048, 4096, bs);
}

// Round 2
// 1795.077 us; speedup vs baseline: 2.5031x; 2.5031x over previous
//
#include <hip/hip_runtime.h>
#include <stdint.h>
#include <stddef.h>

// ESTHead: B=4 S=2048 HID=4096 H=32 D=128
// Pipeline:
//   rope_table (cos/sin LUT)  +  f2b(X, Wk, Wv) -> bf16
//   gemm_rope: k = rope(X@Wk^T), v = rope(X@Wv^T)   [bf16 MFMA 16x16x32, 128x128 tile, BK=64]
//   scores = eq . k ; softmax ; attn_out = p . v
//   fp32 skinny tail: Wo -> LN -> (W0,W1,SiLU) -> W2 -> LN -> Ws + bs
//
// R1 lesson: sincosf in the GEMM epilogue = libm call -> acc spills (8 GB scratch
// writes/dispatch, VGPR capped at 80, MfmaUtil 6%). RoPE trig now comes from a
// precomputed LUT; epilogue is loads+FMAs only.

#define BB 4
#define SS 2048
#define HIDDIM 4096
#define NH 32
#define HD 128
#define MROWS (BB * SS)  // 8192

typedef __attribute__((ext_vector_type(8))) __bf16 bf16x8;
typedef __attribute__((ext_vector_type(4))) float f32x4;

static __device__ __forceinline__ unsigned short f2bf(float f) {
  union { float f; unsigned u; } c; c.f = f;
  unsigned u = c.u;
  u += 0x7fffu + ((u >> 16) & 1u);
  return (unsigned short)(u >> 16);
}
static __device__ __forceinline__ float bf2f(unsigned short h) {
  union { unsigned u; float f; } c; c.u = ((unsigned)h) << 16;
  return c.f;
}

// LUT: cos/sin of s * 10000^(-ip/64), s in [0,2048), ip in [0,64)
__global__ __launch_bounds__(256) void rope_table_kernel(float* __restrict__ cs,
                                                         float* __restrict__ sn) {
  int idx = blockIdx.x * 256 + threadIdx.x;
  int s = idx >> 6, ip = idx & 63;
  float theta = exp2f(-0.2076205059304601f * (float)ip);  // log2(10000)/64
  float ph = (float)s * theta;
  cs[idx] = cosf(ph);
  sn[idx] = sinf(ph);
}

__global__ __launch_bounds__(256) void f2b_kernel(const float4* __restrict__ in,
                                                  ushort4* __restrict__ out, int n4) {
  int stride = gridDim.x * blockDim.x;
  for (int i = blockIdx.x * blockDim.x + threadIdx.x; i < n4; i += stride) {
    float4 v = in[i];
    ushort4 o;
    o.x = f2bf(v.x); o.y = f2bf(v.y); o.z = f2bf(v.z); o.w = f2bf(v.w);
    out[i] = o;
  }
}

static __device__ __forceinline__ void load16_lds(const void* g, void* l) {
  __builtin_amdgcn_global_load_lds(
      (const __attribute__((address_space(1))) unsigned int*)g,
      (__attribute__((address_space(3))) unsigned int*)l, 16, 0, 0);
}

// C = rope(A @ W^T) in bf16. A: 8192x4096 bf16, W: 4096x4096 bf16 (both K-contiguous).
// Block: 256 thr = 4 waves (2x2), 128x128 tile, BK=64, single LDS buffer, 2 barriers/iter.
// LDS chunk XOR-swizzle: slot jj of row holds global chunk (jj ^ (row&7)) so the
// ds_read_b128 fragment reads hit <=2-way bank conflicts (free) despite no padding.
__global__ __launch_bounds__(256) void gemm_rope_kernel(
    const unsigned short* __restrict__ A,
    const unsigned short* __restrict__ W,
    const float* __restrict__ rope_cs,
    const float* __restrict__ rope_sn,
    unsigned short* __restrict__ C) {
  __shared__ __align__(16) unsigned char smem[32768];
  unsigned char* sA = smem;
  unsigned char* sB = smem + 16384;

  const int tid  = threadIdx.x;
  const int wave = tid >> 6;
  const int lane = tid & 63;
  const int wm = wave >> 1, wn = wave & 1;
  const int quad = lane >> 4, l15 = lane & 15;
  const int bm = blockIdx.y, bn = blockIdx.x;

  f32x4 acc[4][4];
#pragma unroll
  for (int i = 0; i < 4; ++i)
#pragma unroll
    for (int j = 0; j < 4; ++j)
      acc[i][j] = (f32x4){0.f, 0.f, 0.f, 0.f};

  const int crow = lane >> 3;      // row within 8-row staging chunk
  const int jj   = lane & 7;       // LDS 16B slot within row
  const int scol = jj ^ crow;      // swizzled global chunk to fetch
  const unsigned short* Abase = A + (size_t)(bm * 128) * HIDDIM;
  const unsigned short* Wbase = W + (size_t)(bn * 128) * HIDDIM;

  for (int kt = 0; kt < HIDDIM; kt += 64) {
#pragma unroll
    for (int it = 0; it < 4; ++it) {
      int rt = wave * 32 + it * 8 + crow;          // tile row 0..127
      int lo = (wave * 4 + it) * 1024;             // wave-uniform LDS chunk base
      load16_lds(Abase + (size_t)rt * HIDDIM + kt + scol * 8, sA + lo);
      load16_lds(Wbase + (size_t)rt * HIDDIM + kt + scol * 8, sB + lo);
    }
    __syncthreads();  // vmcnt(0) drain + barrier: LDS tiles ready
#pragma unroll
    for (int ks = 0; ks < 2; ++ks) {
      const int ch = ((ks * 4 + quad) ^ (l15 & 7)) * 16;
      bf16x8 af[4], bfr[4];
#pragma unroll
      for (int i = 0; i < 4; ++i) {
        int arow = wm * 64 + i * 16 + l15;
        af[i] = *(const bf16x8*)(sA + arow * 128 + ch);
      }
#pragma unroll
      for (int j = 0; j < 4; ++j) {
        int brow = wn * 64 + j * 16 + l15;
        bfr[j] = *(const bf16x8*)(sB + brow * 128 + ch);
      }
#pragma unroll
      for (int i = 0; i < 4; ++i)
#pragma unroll
        for (int j = 0; j < 4; ++j)
          acc[i][j] = __builtin_amdgcn_mfma_f32_16x16x32_bf16(af[i], bfr[j], acc[i][j], 0, 0, 0);
    }
    __syncthreads();  // all waves done reading before next overwrite
  }

  // Epilogue: RoPE (LUT) + packed bf16x2 store. C/D layout: col = lane&15, row = quad*4+reg.
  // N-tile (128) == head dim, so d = col_local; RoPE pair (2i,2i+1) = adjacent lanes.
  const int colb = bn * 128;
#pragma unroll
  for (int j = 0; j < 4; ++j) {
    const int col_local = wn * 64 + j * 16 + l15;  // == d in [0,128)
    const int ip  = col_local >> 1;
    const int odd = col_local & 1;
#pragma unroll
    for (int i = 0; i < 4; ++i) {
#pragma unroll
      for (int r = 0; r < 4; ++r) {
        int token = bm * 128 + wm * 64 + i * 16 + quad * 4 + r;
        int spos  = token & (SS - 1);
        float cs = rope_cs[spos * 64 + ip];
        float sn = rope_sn[spos * 64 + ip];
        float val = acc[i][j][r];
        float oth = __shfl_xor(val, 1);
        float o = odd ? (val * cs + oth * sn) : (val * cs - oth * sn);
        float o_pair = __shfl_xor(o, 1);  // even lane grabs odd lane's result
        if (!odd) {
          unsigned int packed = (unsigned int)f2bf(o) | ((unsigned int)f2bf(o_pair) << 16);
          *(unsigned int*)(C + (size_t)token * HIDDIM + colb + col_local) = packed;
        }
      }
    }
  }
}

// scores[b,h,s] = sum_d eq[h,d] * k[b,s,h,d]; one wave per (b,h,s)
__global__ __launch_bounds__(256) void scores_kernel(const unsigned short* __restrict__ kb,
                                                     const float* __restrict__ eq,
                                                     float* __restrict__ scores) {
  int gw   = blockIdx.x * 4 + (threadIdx.x >> 6);  // (b*32+h)*2048 + s
  int lane = threadIdx.x & 63;
  int s = gw & (SS - 1);
  int h = (gw >> 11) & (NH - 1);
  int b = gw >> 16;
  const unsigned short* kp = kb + (size_t)(b * SS + s) * HIDDIM + h * HD + lane * 2;
  const float* qp = eq + h * HD + lane * 2;
  float p = bf2f(kp[0]) * qp[0] + bf2f(kp[1]) * qp[1];
#pragma unroll
  for (int off = 32; off > 0; off >>= 1) p += __shfl_down(p, off);
  if (lane == 0) scores[gw] = p;
}

// One block per (b,h): softmax over S then attn_out[d] = sum_s p_s * v[b,s,h,d]
__global__ __launch_bounds__(256) void softmax_av_kernel(const float* __restrict__ scores,
                                                         const unsigned short* __restrict__ vb,
                                                         float* __restrict__ attn_out) {
  __shared__ float p[SS];
  __shared__ float red[8];
  __shared__ float acc2[HD];
  const int bh = blockIdx.x, b = bh >> 5, h = bh & 31;
  const int tid = threadIdx.x, lane = tid & 63, wave = tid >> 6;
  const float* sc = scores + (size_t)bh * SS;

  float m = -1e30f;
  for (int i = tid; i < SS; i += 256) m = fmaxf(m, sc[i]);
#pragma unroll
  for (int off = 32; off > 0; off >>= 1) m = fmaxf(m, __shfl_down(m, off));
  if (lane == 0) red[wave] = m;
  __syncthreads();
  if (tid == 0) red[4] = fmaxf(fmaxf(red[0], red[1]), fmaxf(red[2], red[3]));
  __syncthreads();
  const float M = red[4];

  float lsum = 0.f;
  for (int i = tid; i < SS; i += 256) { float e = expf(sc[i] - M); p[i] = e; lsum += e; }
#pragma unroll
  for (int off = 32; off > 0; off >>= 1) lsum += __shfl_down(lsum, off);
  __syncthreads();
  if (lane == 0) red[wave] = lsum;
  __syncthreads();
  const float Ssum = red[0] + red[1] + red[2] + red[3];

  const int d = tid & 127, half = tid >> 7;
  const unsigned short* vp = vb + (size_t)(b * SS) * HIDDIM + h * HD + d;
  float a = 0.f;
  const int s0 = half * 1024;
#pragma unroll 4
  for (int s = s0; s < s0 + 1024; ++s) a += p[s] * bf2f(vp[(size_t)s * HIDDIM]);
  if (half) acc2[d] = a;
  __syncthreads();
  if (!half) attn_out[(size_t)b * HIDDIM + h * HD + d] = (a + acc2[d]) / Ssum;
}

// y[b,n] = sum_k x[b,k]*W[n,k] (+bias). x: 4xK fp32. One wave per n.
__global__ __launch_bounds__(256) void skinny_kernel(const float* __restrict__ W,
                                                     const float* __restrict__ x,
                                                     float* __restrict__ y,
                                                     int N, int K,
                                                     const float* __restrict__ bias) {
  int n = blockIdx.x * 4 + (threadIdx.x >> 6);
  int lane = threadIdx.x & 63;
  const float* w  = W + (size_t)n * K;
  const float* x1 = x + K, * x2 = x + 2 * K, * x3 = x + 3 * K;
  float a0 = 0.f, a1 = 0.f, a2 = 0.f, a3 = 0.f;
#pragma unroll 4
  for (int k = lane; k < K; k += 64) {
    float wv = w[k];
    a0 += wv * x[k]; a1 += wv * x1[k]; a2 += wv * x2[k]; a3 += wv * x3[k];
  }
#pragma unroll
  for (int off = 32; off > 0; off >>= 1) {
    a0 += __shfl_down(a0, off); a1 += __shfl_down(a1, off);
    a2 += __shfl_down(a2, off); a3 += __shfl_down(a3, off);
  }
  if (lane == 0) {
    float bv = bias ? bias[n] : 0.f;
    y[n] = a0 + bv; y[N + n] = a1 + bv; y[2 * N + n] = a2 + bv; y[3 * N + n] = a3 + bv;
  }
}

// c[b,n] = (x@W0^T) * silu(x@W1^T), fused
__global__ __launch_bounds__(256) void skinny_glu_kernel(const float* __restrict__ W0,
                                                         const float* __restrict__ W1,
                                                         const float* __restrict__ x,
                                                         float* __restrict__ c,
                                                         int N, int K) {
  int n = blockIdx.x * 4 + (threadIdx.x >> 6);
  int lane = threadIdx.x & 63;
  const float* w0 = W0 + (size_t)n * K;
  const float* w1 = W1 + (size_t)n * K;
  const float* x1 = x + K, * x2 = x + 2 * K, * x3 = x + 3 * K;
  float a0 = 0.f, a1 = 0.f, a2 = 0.f, a3 = 0.f;
  float g0 = 0.f, g1 = 0.f, g2 = 0.f, g3 = 0.f;
#pragma unroll 2
  for (int k = lane; k < K; k += 64) {
    float wa = w0[k], wg = w1[k];
    float v0 = x[k], v1 = x1[k], v2 = x2[k], v3 = x3[k];
    a0 += wa * v0; a1 += wa * v1; a2 += wa * v2; a3 += wa * v3;
    g0 += wg * v0; g1 += wg * v1; g2 += wg * v2; g3 += wg * v3;
  }
#pragma unroll
  for (int off = 32; off > 0; off >>= 1) {
    a0 += __shfl_down(a0, off); a1 += __shfl_down(a1, off);
    a2 += __shfl_down(a2, off); a3 += __shfl_down(a3, off);
    g0 += __shfl_down(g0, off); g1 += __shfl_down(g1, off);
    g2 += __shfl_down(g2, off); g3 += __shfl_down(g3, off);
  }
  if (lane == 0) {
    c[n]         = a0 * (g0 / (1.f + expf(-g0)));
    c[N + n]     = a1 * (g1 / (1.f + expf(-g1)));
    c[2 * N + n] = a2 * (g2 / (1.f + expf(-g2)));
    c[3 * N + n] = a3 * (g3 / (1.f + expf(-g3)));
  }
}

__global__ __launch_bounds__(256) void ln_kernel(const float* __restrict__ x,
                                                 const float* __restrict__ g,
                                                 const float* __restrict__ bta,
                                                 float* __restrict__ y) {
  __shared__ float rs[8], rs2[8];
  const int b = blockIdx.x, tid = threadIdx.x, lane = tid & 63, wave = tid >> 6;
  const float* xr = x + (size_t)b * HIDDIM;
  float s = 0.f, s2 = 0.f;
  for (int i = tid; i < HIDDIM; i += 256) { float v = xr[i]; s += v; s2 += v * v; }
#pragma unroll
  for (int off = 32; off > 0; off >>= 1) { s += __shfl_down(s, off); s2 += __shfl_down(s2, off); }
  if (lane == 0) { rs[wave] = s; rs2[wave] = s2; }
  __syncthreads();
  if (tid == 0) { rs[4] = rs[0] + rs[1] + rs[2] + rs[3]; rs2[4] = rs2[0] + rs2[1] + rs2[2] + rs2[3]; }
  __syncthreads();
  const float mu = rs[4] * (1.f / HIDDIM);
  const float var = rs2[4] * (1.f / HIDDIM) - mu * mu;
  const float rstd = rsqrtf(var + 1e-5f);
  float* yr = y + (size_t)b * HIDDIM;
  for (int i = tid; i < HIDDIM; i += 256) yr[i] = (xr[i] - mu) * rstd * g[i] + bta[i];
}

extern "C" void kernel_launch(void* const* d_in, const int* in_sizes, int n_in,
                              void* d_out, int out_size, void* d_ws, size_t ws_size,
                              hipStream_t stream) {
  const float* hidden = (const float*)d_in[0];
  const float* eq     = (const float*)d_in[1];
  const float* Wk     = (const float*)d_in[2];
  const float* Wv     = (const float*)d_in[3];
  const float* Wo     = (const float*)d_in[4];
  const float* W0     = (const float*)d_in[5];
  const float* W1     = (const float*)d_in[6];
  const float* W2     = (const float*)d_in[7];
  const float* Ws     = (const float*)d_in[8];
  const float* bs     = (const float*)d_in[9];
  const float* ln_g   = (const float*)d_in[10];
  const float* ln_b   = (const float*)d_in[11];
  float* out = (float*)d_out;

  char* ws = (char*)d_ws;
  unsigned short* Xb   = (unsigned short*)(ws);               // 8192x4096 bf16 = 64 MiB
  unsigned short* Wkb  = (unsigned short*)(ws + 67108864);    // 32 MiB
  unsigned short* Wvb  = (unsigned short*)(ws + 100663296);   // 32 MiB
  unsigned short* kb   = (unsigned short*)(ws + 134217728);   // 64 MiB (roped k, bf16)
  unsigned short* vb   = (unsigned short*)(ws + 201326592);   // 64 MiB (roped v, bf16)
  float* scores  = (float*)(ws + 268435456);                  // 4*32*2048 fp32 = 1 MiB
  float* attn    = (float*)(ws + 269484032);                  // 4x4096
  float* y1      = (float*)(ws + 269549568);
  float* x1      = (float*)(ws + 269615104);
  float* cbuf    = (float*)(ws + 269680640);                  // 4x12288
  float* y2      = (float*)(ws + 269877248);
  float* x2      = (float*)(ws + 269942784);
  float* ropeC   = (float*)(ws + 270008320);                  // 2048*64 fp32
  float* ropeS   = (float*)(ws + 270532608);                  // 2048*64 fp32
  (void)in_sizes; (void)n_in; (void)out_size; (void)ws_size;

  rope_table_kernel<<<512, 256, 0, stream>>>(ropeC, ropeS);
  f2b_kernel<<<8192, 256, 0, stream>>>((const float4*)hidden, (ushort4*)Xb, (MROWS * HIDDIM) / 4);
  f2b_kernel<<<4096, 256, 0, stream>>>((const float4*)Wk, (ushort4*)Wkb, (4096 * HIDDIM) / 4);
  f2b_kernel<<<4096, 256, 0, stream>>>((const float4*)Wv, (ushort4*)Wvb, (4096 * HIDDIM) / 4);

  dim3 gg(32, 64);  // bn x bm
  gemm_rope_kernel<<<gg, 256, 0, stream>>>(Xb, Wkb, ropeC, ropeS, kb);
  gemm_rope_kernel<<<gg, 256, 0, stream>>>(Xb, Wvb, ropeC, ropeS, vb);

  scores_kernel<<<(BB * NH * SS) / 4, 256, 0, stream>>>(kb, eq, scores);
  softmax_av_kernel<<<BB * NH, 256, 0, stream>>>(scores, vb, attn);

  skinny_kernel<<<4096 / 4, 256, 0, stream>>>(Wo, attn, y1, 4096, 4096, nullptr);
  ln_kernel<<<BB, 256, 0, stream>>>(y1, ln_g, ln_b, x1);
  skinny_glu_kernel<<<12288 / 4, 256, 0, stream>>>(W0, W1, x1, cbuf, 12288, 4096);
  skinny_kernel<<<4096 / 4, 256, 0, stream>>>(W2, cbuf, y2, 4096, 12288, nullptr);
  ln_kernel<<<BB, 256, 0, stream>>>(y2, ln_g, ln_b, x2);
  skinny_kernel<<<2048 / 4, 256, 0, stream>>>(Ws, x2, out, 2048, 4096, bs);
}